// Round 11
// 2340.012 us; speedup vs baseline: 9.9049x; 1.0152x over previous
//
#include <hip/hip_runtime.h>
#include <cmath>

// ---------------- problem constants ----------------
#define BB 32          // batch
#define NPTS 8192      // points per cloud
#define NG 128         // groups
#define KNB 32         // neighbors per group
#define LK 32          // len_keep
#define DE 768         // encoder dim
#define DD 512         // decoder dim
#define NLE 12
#define NLD 8

typedef __bf16 bf16x8 __attribute__((ext_vector_type(8)));
typedef float  f32x4  __attribute__((ext_vector_type(4)));
typedef unsigned long long u64;

#define WAITV(N) asm volatile("s_waitcnt vmcnt(" #N ")" ::: "memory")

static __device__ __forceinline__ bf16x8 pack8(float4 a, float4 b) {
    bf16x8 h;
    h[0] = (__bf16)a.x; h[1] = (__bf16)a.y; h[2] = (__bf16)a.z; h[3] = (__bf16)a.w;
    h[4] = (__bf16)b.x; h[5] = (__bf16)b.y; h[6] = (__bf16)b.z; h[7] = (__bf16)b.w;
    return h;
}

// async global->LDS 16B copy: per-wave, lane l writes ldsbase + l*16
static __device__ __forceinline__ void gload16(const __bf16* g, __bf16* l) {
    __builtin_amdgcn_global_load_lds(
        (const __attribute__((address_space(1))) void*)g,
        (__attribute__((address_space(3))) void*)l,
        16, 0, 0);
}

// monotone float -> uint map (total order preserved, handles negatives)
static __device__ __forceinline__ unsigned fkey(float f) {
    unsigned u = __float_as_uint(f);
    return ((int)u < 0) ? ~u : (u | 0x80000000u);
}

// =====================================================================
// FPS (at serial-latency floor): one block/batch, 512 thr, regs + 1 barrier/step
// =====================================================================
__global__ __launch_bounds__(512, 1) void fps_kernel(
    const float* __restrict__ xyz, const int* __restrict__ init,
    float* __restrict__ cxyz)
{
#pragma clang fp contract(off)
    const int b = blockIdx.x;
    const float* P = xyz + (size_t)b * NPTS * 3;
    __shared__ float pxs[NPTS], pys[NPTS], pzs[NPTS];
    __shared__ u64 red[2][8];
    const int tid = threadIdx.x;
    float x[16], y[16], z[16], dmin[16];
    #pragma unroll
    for (int k = 0; k < 16; ++k) {
        int n = tid + (k << 9);
        float xx = P[n * 3 + 0], yy = P[n * 3 + 1], zz = P[n * 3 + 2];
        x[k] = xx; y[k] = yy; z[k] = zz;
        pxs[n] = xx; pys[n] = yy; pzs[n] = zz;
        dmin[k] = 1e10f;
    }
    int far = init[b];
    __syncthreads();
    for (int t = 0; t < NG; ++t) {
        float cx = pxs[far], cy = pys[far], cz = pzs[far];
        if (tid == 0) {
            cxyz[(b * NG + t) * 3 + 0] = cx;
            cxyz[(b * NG + t) * 3 + 1] = cy;
            cxyz[(b * NG + t) * 3 + 2] = cz;
        }
        float best = -1.0f; int bi = 0;
        #pragma unroll
        for (int k = 0; k < 16; ++k) {
            int n = tid + (k << 9);
            float dx = x[k] - cx, dy = y[k] - cy, dz = z[k] - cz;
            float d = dx * dx + dy * dy + dz * dz;
            float dm = dmin[k];
            if (d < dm) dm = d;
            dmin[k] = dm;
            if (dm > best) { best = dm; bi = n; }   // strict > keeps lowest index
        }
        u64 key = ((u64)__float_as_uint(best) << 32) | (unsigned)(8191 - bi);
        #pragma unroll
        for (int d = 32; d >= 1; d >>= 1) {
            u64 k2 = __shfl_down(key, d);
            if (k2 > key) key = k2;
        }
        if ((tid & 63) == 0) red[t & 1][tid >> 6] = key;
        __syncthreads();
        u64 kb = red[t & 1][0];
        #pragma unroll
        for (int w = 1; w < 8; ++w) {
            u64 k2 = red[t & 1][w];
            if (k2 > kb) kb = k2;
        }
        far = 8191 - (int)(kb & 0xFFFFFFFFu);
    }
}

// =====================================================================
// KNN: threshold + rank selection (unchanged).
// =====================================================================
__global__ __launch_bounds__(256) void knn_kernel(
    const float* __restrict__ xyz, const float* __restrict__ cxyz,
    float* __restrict__ gn)
{
#pragma clang fp contract(off)
    const int bm = blockIdx.x;
    const int b = bm / NG;
    const float* P = xyz + (size_t)b * NPTS * 3;
    __shared__ u64 cand[512];
    __shared__ u64 tmins[4];
    __shared__ int wcnt[4];
    __shared__ int order[KNB];
    const int tid = threadIdx.x;
    const int wv = tid >> 6, lane = tid & 63;
    const float cx = cxyz[bm * 3 + 0], cy = cxyz[bm * 3 + 1], cz = cxyz[bm * 3 + 2];
    const float c2 = cx * cx + cy * cy + cz * cz;
    unsigned fk[32];
    float bestf = 1e31f; int bi = 1 << 30;
    #pragma unroll
    for (int j = 0; j < 32; ++j) {
        int n = tid + (j << 8);
        float x = P[n * 3 + 0], y = P[n * 3 + 1], z = P[n * 3 + 2];
        float x2 = x * x + y * y + z * z;
        float dt = cx * x + cy * y + cz * z;
        float v = (c2 + x2) - 2.0f * dt;
        fk[j] = fkey(v);
        if (v < bestf) { bestf = v; bi = n; }
    }
    u64 mk = ((u64)fkey(bestf) << 32) | (unsigned)bi;
    {
        u64 v = mk;
        #pragma unroll
        for (int k = 2; k <= 64; k <<= 1) {
            #pragma unroll
            for (int j = k >> 1; j > 0; j >>= 1) {
                u64 o = __shfl_xor(v, j);
                bool up = ((lane & k) == 0);
                bool lower = ((lane & j) == 0);
                u64 mn = (v < o) ? v : o;
                u64 mx = (v < o) ? o : v;
                v = (up == lower) ? mn : mx;
            }
        }
        u64 Tw = __shfl(v, 31);
        if (lane == 0) tmins[wv] = Tw;
    }
    __syncthreads();
    u64 T = tmins[0];
    #pragma unroll
    for (int w = 1; w < 4; ++w) { u64 k2 = tmins[w]; if (k2 < T) T = k2; }
    int c = 0;
    #pragma unroll
    for (int j = 0; j < 32; ++j) {
        u64 key = ((u64)fk[j] << 32) | (unsigned)(tid + (j << 8));
        c += (key <= T) ? 1 : 0;
    }
    int s = c;
    #pragma unroll
    for (int d = 1; d < 64; d <<= 1) {
        int t2 = __shfl_up(s, d);
        if (lane >= d) s += t2;
    }
    int excl = s - c;
    if (lane == 63) wcnt[wv] = s;
    __syncthreads();
    int base = 0;
    for (int w = 0; w < wv; ++w) base += wcnt[w];
    int etot = wcnt[0] + wcnt[1] + wcnt[2] + wcnt[3];

    if (etot <= 512) {
        int pos = base + excl;
        #pragma unroll
        for (int j = 0; j < 32; ++j) {
            u64 key = ((u64)fk[j] << 32) | (unsigned)(tid + (j << 8));
            if (key <= T) cand[pos++] = key;
        }
        __syncthreads();
        for (int si = tid; si < etot; si += 256) {
            u64 my = cand[si];
            int r = 0;
            for (int j2 = 0; j2 < etot; ++j2) r += (cand[j2] < my) ? 1 : 0;
            if (r < KNB) order[r] = (int)(my & 0xFFFFFFFFu);
        }
        __syncthreads();
    } else {
        u64 bk = ~0ull;
        #pragma unroll
        for (int j = 0; j < 32; ++j) {
            u64 key = ((u64)fk[j] << 32) | (unsigned)(tid + (j << 8));
            if (key < bk) bk = key;
        }
        for (int r = 0; r < KNB; ++r) {
            u64 kk = bk;
            #pragma unroll
            for (int dd = 32; dd >= 1; dd >>= 1) {
                u64 k2 = __shfl_down(kk, dd);
                if (k2 < kk) kk = k2;
            }
            if (lane == 0) cand[(r & 1) * 4 + wv] = kk;
            __syncthreads();
            u64 kb = cand[(r & 1) * 4 + 0];
            #pragma unroll
            for (int w = 1; w < 4; ++w) { u64 k2 = cand[(r & 1) * 4 + w]; if (k2 < kb) kb = k2; }
            if (tid == 0) order[r] = (int)(kb & 0xFFFFFFFFu);
            if ((int)(kb & 255u) == tid) {
                int sj = (int)((kb & 0xFFFFFFFFu) >> 8);
                #pragma unroll
                for (int j = 0; j < 32; ++j) if (j == sj) fk[j] = 0xFFFFFFFFu;
                bk = ~0ull;
                #pragma unroll
                for (int j = 0; j < 32; ++j) {
                    u64 key = ((u64)fk[j] << 32) | (unsigned)(tid + (j << 8));
                    if (key < bk) bk = key;
                }
            }
            __syncthreads();
        }
    }
    if (tid < KNB) {
        int n = order[tid];
        gn[((size_t)bm * KNB + tid) * 3 + 0] = P[n * 3 + 0] - cx;
        gn[((size_t)bm * KNB + tid) * 3 + 1] = P[n * 3 + 1] - cy;
        gn[((size_t)bm * KNB + tid) * 3 + 2] = P[n * 3 + 2] - cz;
    }
}

// =====================================================================
// f32 -> bf16 bulk convert
// =====================================================================
__global__ void cvt_bf16_kernel(const float* __restrict__ src, __bf16* __restrict__ dst, int n8)
{
    int i = blockIdx.x * 256 + threadIdx.x;
    if (i >= n8) return;
    const float4* p = (const float4*)(src + (size_t)i * 8);
    *(bf16x8*)(dst + (size_t)i * 8) = pack8(p[0], p[1]);
}

struct CvtTab {
    const float* src[10];
    __bf16* dst[10];
    int cum[11];
};
__global__ void cvt_multi_kernel(CvtTab t)
{
    int i = blockIdx.x * 256 + threadIdx.x;
    if (i >= t.cum[10]) return;
    int seg = 0;
    #pragma unroll
    for (int k = 1; k < 10; ++k) seg += (i >= t.cum[k]) ? 1 : 0;
    int local = i - t.cum[seg];
    const float4* p = (const float4*)(t.src[seg] + (size_t)local * 8);
    *(bf16x8*)(t.dst[seg] + (size_t)local * 8) = pack8(p[0], p[1]);
}

// =====================================================================
// embed1
// =====================================================================
__global__ void embed1_kernel(const float* __restrict__ gn, const float* __restrict__ w,
                              const float* __restrict__ bias, float* __restrict__ h1)
{
    int i = blockIdx.x * 256 + threadIdx.x;
    if (i >= 131072 * 64) return;
    int r = i >> 6, c = i & 63;
    const float* p = gn + (size_t)r * 3;
    h1[i] = p[0] * w[c * 3 + 0] + p[1] * w[c * 3 + 1] + p[2] * w[c * 3 + 2] + bias[c];
}

// =====================================================================
// column stats (C=64 path for h1 only)
// =====================================================================
template <int C>
__global__ __launch_bounds__(256) void colstats_kernel(const float* __restrict__ X,
                                                       double* __restrict__ st, int Mrows)
{
    constexpr int RL = 256 / C;
    const int c = threadIdx.x % C;
    const int rl = threadIdx.x / C;
    double s = 0.0, s2 = 0.0;
    int rows_per_block = (Mrows + gridDim.x - 1) / gridDim.x;
    int r0 = blockIdx.x * rows_per_block;
    int r1 = min(r0 + rows_per_block, Mrows);
    for (int r = r0 + rl; r < r1; r += RL) {
        float v = X[(size_t)r * C + c];
        s += v; s2 += (double)v * v;
    }
    __shared__ double sh[2][256];
    sh[0][threadIdx.x] = s; sh[1][threadIdx.x] = s2;
    __syncthreads();
    if (rl == 0) {
        for (int j = 1; j < RL; ++j) { s += sh[0][j * C + c]; s2 += sh[1][j * C + c]; }
        atomicAdd(&st[c], s);
        atomicAdd(&st[C + c], s2);
    }
}

__global__ void bn_finalize(const double* __restrict__ st, const float* __restrict__ g,
                            const float* __restrict__ be, float* __restrict__ sc,
                            float* __restrict__ shb, int C)
{
    int c = blockIdx.x * 64 + threadIdx.x;
    if (c >= C) return;
    double m = st[c] / 131072.0;
    double var = st[C + c] / 131072.0 - m * m;
    if (var < 0.0) var = 0.0;
    float rs = rsqrtf((float)var + 1e-5f);
    sc[c] = rs * g[c];
    shb[c] = be[c] - (float)m * rs * g[c];
}

// finalize for 32-way spread stats layout: st[p*2*C + {c, C+c}], p=0..31
__global__ void bn_spread_finalize(const double* __restrict__ st, const float* __restrict__ g,
                                   const float* __restrict__ be, float* __restrict__ sc,
                                   float* __restrict__ shb, int C)
{
    int c = blockIdx.x * 64 + threadIdx.x;
    if (c >= C) return;
    double s = 0.0, s2 = 0.0;
    for (int p = 0; p < 32; ++p) {
        s  += st[(size_t)p * 2 * C + c];
        s2 += st[(size_t)p * 2 * C + C + c];
    }
    double m = s / 131072.0;
    double var = s2 / 131072.0 - m * m;
    if (var < 0.0) var = 0.0;
    float rs = rsqrtf((float)var + 1e-5f);
    sc[c] = rs * g[c];
    shb[c] = be[c] - (float)m * rs * g[c];
}

__global__ void bn_apply_bf16(const float* __restrict__ x, const float* __restrict__ sc,
                              const float* __restrict__ shb, __bf16* __restrict__ y,
                              int total, int C)
{
    int i = blockIdx.x * 256 + threadIdx.x;
    if (i >= total) return;
    int c = i % C;
    float v = x[i] * sc[c] + shb[c];
    v = fmaxf(v, 0.0f);
    y[i] = (__bf16)v;
}

// =====================================================================
// bf16 MFMA GEMM, split-K, single-barrier counted-vmcnt pipeline.
// STATS: fused per-column sum/sumsq (double, 32-spread atomics) for the
// BN-stats GEMM (requires grid.x==1 so the block sees all N columns).
// =====================================================================
template <int BM, int WM, int WN, int DEPTH, bool STATS>
__global__ __launch_bounds__(256) void gemm_bf16(
    const __bf16* __restrict__ A, const __bf16* __restrict__ W,
    const float* __restrict__ bias, float* __restrict__ Cf, __bf16* __restrict__ Cb,
    int M, int N, int K, int Kc, int relu, double* __restrict__ st)
{
    constexpr int MR = BM / WM / 16;
    constexpr int NR = 128 / WN / 16;
    constexpr int CA = BM * 8 / 256;
    __shared__ __bf16 As[DEPTH][BM * 64];
    __shared__ __bf16 Ws[DEPTH][128 * 64];
    const int tid = threadIdx.x;
    const int lane = tid & 63;
    const int wave = tid >> 6;
    const int wm = wave / WN, wn = wave % WN;
    const int m0 = blockIdx.y * BM, n0 = blockIdx.x * 128;
    const int kb = blockIdx.z * Kc;

    f32x4 acc[MR][NR] = {};

    auto stage = [&](int buf, int kt) {
        #pragma unroll
        for (int j = 0; j < CA; ++j) {
            int cb = j * 256 + (wave << 6);
            int c  = cb + lane;
            int row = c >> 3;
            int kcs = (c & 7) ^ (row & 7);
            gload16(A + (size_t)(m0 + row) * K + kb + kt + kcs * 8, &As[buf][cb * 8]);
        }
        #pragma unroll
        for (int j = 0; j < 4; ++j) {
            int cb = j * 256 + (wave << 6);
            int c  = cb + lane;
            int row = c >> 3;
            int kcs = (c & 7) ^ (row & 7);
            gload16(W + (size_t)(n0 + row) * K + kb + kt + kcs * 8, &Ws[buf][cb * 8]);
        }
    };
    auto compute = [&](int buf) {
        #pragma unroll
        for (int ks = 0; ks < 2; ++ks) {
            bf16x8 af[MR], bfr[NR];
            int kc = ks * 4 + (lane >> 4);
            #pragma unroll
            for (int i = 0; i < MR; ++i) {
                int rowA = wm * (BM / WM) + i * 16 + (lane & 15);
                af[i] = *(bf16x8*)&As[buf][rowA * 64 + ((kc ^ (rowA & 7)) * 8)];
            }
            #pragma unroll
            for (int j = 0; j < NR; ++j) {
                int rowB = wn * (128 / WN) + j * 16 + (lane & 15);
                bfr[j] = *(bf16x8*)&Ws[buf][rowB * 64 + ((kc ^ (rowB & 7)) * 8)];
            }
            #pragma unroll
            for (int i = 0; i < MR; ++i)
                #pragma unroll
                for (int j = 0; j < NR; ++j)
                    acc[i][j] = __builtin_amdgcn_mfma_f32_16x16x32_bf16(af[i], bfr[j], acc[i][j], 0, 0, 0);
        }
    };

    const int nt = Kc >> 6;
    stage(0, 0);
    if (DEPTH > 2 && nt > 1) stage(1, 64);
    for (int t = 0; t < nt; ++t) {
        int ahead = min(nt - 1, t + DEPTH - 2) - t;
        if (ahead >= 1) { if constexpr (BM == 64) WAITV(6); else WAITV(8); }
        else            WAITV(0);
        __syncthreads();
        if (t + DEPTH - 1 < nt) stage((t + DEPTH - 1) % DEPTH, (t + DEPTH - 1) << 6);
        compute(t % DEPTH);
    }

    float* Co = Cf ? Cf + (size_t)blockIdx.z * M * N : nullptr;
    #pragma unroll
    for (int j = 0; j < NR; ++j) {
        int col = n0 + wn * (128 / WN) + j * 16 + (lane & 15);
        if (col >= N) continue;
        float bv = (blockIdx.z == 0) ? bias[col] : 0.0f;
        float s = 0.0f, s2 = 0.0f;
        #pragma unroll
        for (int i = 0; i < MR; ++i) {
            #pragma unroll
            for (int r = 0; r < 4; ++r) {
                int rowm = m0 + wm * (BM / WM) + i * 16 + (lane >> 4) * 4 + r;
                float v = acc[i][j][r] + bv;
                if (relu) v = fmaxf(v, 0.0f);
                if (STATS) { s += v; s2 += v * v; }
                if (Co) Co[(size_t)rowm * N + col] = v;
                if (Cb) Cb[(size_t)rowm * N + col] = (__bf16)v;
            }
        }
        if constexpr (STATS) {
            // reduce across the 4 row-groups (lane>>4) within the wave
            #pragma unroll
            for (int d = 16; d < 64; d <<= 1) {
                s  += __shfl_xor(s, d);
                s2 += __shfl_xor(s2, d);
            }
            if (lane < 16) {
                double* stp = st + (size_t)(blockIdx.y & 31) * 2 * 128;
                atomicAdd(&stp[col], (double)s);
                atomicAdd(&stp[128 + col], (double)s2);
            }
        }
    }
}

// =====================================================================
// embed3 via MFMA (unchanged)
// =====================================================================
__global__ __launch_bounds__(256) void embed3_mfma(
    const __bf16* __restrict__ A, const __bf16* __restrict__ W,
    const float* __restrict__ cb3,
    float* __restrict__ gmax, float* __restrict__ gmin, double* __restrict__ st3)
{
    __shared__ __bf16 As[2][128 * 64];
    __shared__ __bf16 Ws[2][128 * 64];
    const int tid = threadIdx.x;
    const int lane = tid & 63;
    const int wave = tid >> 6;
    const int wm = wave >> 1, wn = wave & 1;
    const int m0 = blockIdx.y * 128, n0 = blockIdx.x * 128;
    const int K = 128;

    f32x4 acc[4][4] = {};

    auto stage = [&](int buf, int kt) {
        #pragma unroll
        for (int j = 0; j < 4; ++j) {
            int cb = j * 256 + (wave << 6);
            int c  = cb + lane;
            int row = c >> 3;
            int kcs = (c & 7) ^ (row & 7);
            gload16(A + (size_t)(m0 + row) * K + kt + kcs * 8, &As[buf][cb * 8]);
            gload16(W + (size_t)(n0 + row) * K + kt + kcs * 8, &Ws[buf][cb * 8]);
        }
    };
    auto compute = [&](int buf) {
        #pragma unroll
        for (int ks = 0; ks < 2; ++ks) {
            bf16x8 af[4], bfr[4];
            int kc = ks * 4 + (lane >> 4);
            #pragma unroll
            for (int i = 0; i < 4; ++i) {
                int rowA = wm * 64 + i * 16 + (lane & 15);
                af[i] = *(bf16x8*)&As[buf][rowA * 64 + ((kc ^ (rowA & 7)) * 8)];
                int rowB = wn * 64 + i * 16 + (lane & 15);
                bfr[i] = *(bf16x8*)&Ws[buf][rowB * 64 + ((kc ^ (rowB & 7)) * 8)];
            }
            #pragma unroll
            for (int i = 0; i < 4; ++i)
                #pragma unroll
                for (int j = 0; j < 4; ++j)
                    acc[i][j] = __builtin_amdgcn_mfma_f32_16x16x32_bf16(af[i], bfr[j], acc[i][j], 0, 0, 0);
        }
    };

    stage(0, 0);
    stage(1, 64);
    WAITV(8);
    __syncthreads();
    compute(0);
    WAITV(0);
    __syncthreads();
    compute(1);

    #pragma unroll
    for (int j = 0; j < 4; ++j) {
        int col = n0 + wn * 64 + j * 16 + (lane & 15);
        float bv = cb3[col];
        float stot = 0.0f, s2tot = 0.0f;
        #pragma unroll
        for (int gi = 0; gi < 2; ++gi) {
            float mx = -1e30f, mn = 1e30f, s = 0.0f, s2 = 0.0f;
            #pragma unroll
            for (int ii = 0; ii < 2; ++ii) {
                f32x4 a = acc[gi * 2 + ii][j];
                #pragma unroll
                for (int r = 0; r < 4; ++r) {
                    float v = a[r] + bv;
                    mx = fmaxf(mx, v); mn = fminf(mn, v);
                    s += v; s2 += v * v;
                }
            }
            #pragma unroll
            for (int d = 16; d < 64; d <<= 1) {
                mx = fmaxf(mx, __shfl_xor(mx, d));
                mn = fminf(mn, __shfl_xor(mn, d));
                s  += __shfl_xor(s, d);
                s2 += __shfl_xor(s2, d);
            }
            stot += s; s2tot += s2;
            if (lane < 16) {
                int g = (m0 >> 5) + wm * 2 + gi;
                gmax[(size_t)g * 768 + col] = mx;
                gmin[(size_t)g * 768 + col] = mn;
            }
        }
        if (lane < 16) {
            double* stp = st3 + (size_t)(blockIdx.y & 31) * 1536;
            atomicAdd(&stp[col], (double)stot);
            atomicAdd(&stp[768 + col], (double)s2tot);
        }
    }
}

__global__ void bn3_finalize(const double* __restrict__ st3, const float* __restrict__ g,
                             const float* __restrict__ be, float* __restrict__ a3,
                             float* __restrict__ c3)
{
    int c = blockIdx.x * 256 + threadIdx.x;
    if (c >= 768) return;
    double s = 0.0, s2 = 0.0;
    for (int p = 0; p < 32; ++p) { s += st3[(size_t)p * 1536 + c]; s2 += st3[(size_t)p * 1536 + 768 + c]; }
    double m = s / 131072.0;
    double var = s2 / 131072.0 - m * m;
    if (var < 0.0) var = 0.0;
    float rs = rsqrtf((float)var + 1e-5f);
    a3[c] = rs * g[c];
    c3[c] = be[c] - (float)m * rs * g[c];
}

// tokens + pos, fused gather (kept rows only)
__global__ void tokens_pos(const float* __restrict__ gmax, const float* __restrict__ gmin,
                           const float* __restrict__ a3, const float* __restrict__ c3,
                           const float* __restrict__ cxyz, const float* __restrict__ posw,
                           const float* __restrict__ posb, const int* __restrict__ restore,
                           float* __restrict__ xe, __bf16* __restrict__ xeb)
{
    int i = blockIdx.x * 256 + threadIdx.x;
    if (i >= 4096 * 768) return;
    int c = i % 768, g = i / 768;
    int r = restore[g];
    if (r >= LK) return;
    float a = a3[c];
    float tok = (a >= 0.0f ? a * gmax[i] : a * gmin[i]) + c3[c];
    float px = cxyz[g * 3 + 0], py = cxyz[g * 3 + 1], pz = cxyz[g * 3 + 2];
    float v = tok + px * posw[c * 3 + 0] + py * posw[c * 3 + 1] + pz * posw[c * 3 + 2] + posb[c];
    int b = g >> 7;
    size_t idx = ((size_t)(b * LK + r)) * DE + c;
    xe[idx] = v;
    xeb[idx] = (__bf16)v;
}

__global__ void restore_kernel(const int* __restrict__ shuffle, int* __restrict__ restore,
                               float* __restrict__ maskv)
{
    int j = blockIdx.x * 256 + threadIdx.x;
    if (j >= BB * NG) return;
    int b = j / NG, p = j % NG;
    int dst = b * NG + shuffle[j];
    restore[dst] = p;
    maskv[dst] = (p < LK) ? 0.0f : 1.0f;
}

__global__ void yd_build(const float* __restrict__ ykp, const int* __restrict__ restore,
                         const float* __restrict__ mtok, const float* __restrict__ cxyz,
                         const float* __restrict__ dpw, const float* __restrict__ dpb,
                         float* __restrict__ xd, __bf16* __restrict__ xdb)
{
    const size_t PS = (size_t)1024 * DD;
    int i = blockIdx.x * 256 + threadIdx.x;
    if (i >= BB * NG * DD) return;
    int c = i % DD;
    int g = i / DD;
    int b = g / NG;
    int r = restore[g];
    float base;
    if (r < LK) {
        size_t o = (size_t)(b * LK + r) * DD + c;
        base = ykp[o] + ykp[PS + o] + ykp[2 * PS + o] + ykp[3 * PS + o];
    } else {
        base = mtok[c];
    }
    float px = cxyz[g * 3 + 0], py = cxyz[g * 3 + 1], pz = cxyz[g * 3 + 2];
    float v = base + px * dpw[c * 3 + 0] + py * dpw[c * 3 + 1] + pz * dpw[c * 3 + 2] + dpb[c];
    xd[i] = v;
    xdb[i] = (__bf16)v;
}

// =====================================================================
// decoder attention via MFMA (unchanged)
// =====================================================================
template <int S, int DH, int NH>
__global__ __launch_bounds__(256) void dattn_kernel(const __bf16* __restrict__ qkv,
                                                    __bf16* __restrict__ o, float scale)
{
    constexpr int D = NH * DH;
    constexpr int SQ = DH + 8;
    constexpr int SV = S + 8;
    __shared__ __bf16 Qb[S * SQ];
    __shared__ __bf16 Kb[S * SQ];
    __shared__ __bf16 Vt[DH * SV];
    __shared__ __bf16 Pb[S * SV];
    const int h = blockIdx.x % NH;
    const int b = blockIdx.x / NH;
    const int tid = threadIdx.x;
    const int lane = tid & 63, wv = tid >> 6;
    const __bf16* base = qkv + (size_t)b * S * 3 * D + h * DH;
    for (int i = tid; i < S * (DH / 8); i += 256) {
        int s = i / (DH / 8), c8 = (i % (DH / 8)) * 8;
        const __bf16* rp = base + (size_t)s * 3 * D;
        bf16x8 q = *(const bf16x8*)(rp + c8);
        bf16x8 k = *(const bf16x8*)(rp + D + c8);
        bf16x8 v = *(const bf16x8*)(rp + 2 * D + c8);
        *(bf16x8*)&Qb[s * SQ + c8] = q;
        *(bf16x8*)&Kb[s * SQ + c8] = k;
        #pragma unroll
        for (int j = 0; j < 8; ++j) Vt[(c8 + j) * SV + s] = v[j];
    }
    __syncthreads();
    const int q0 = wv * 32;
    const int arow = lane & 15;
    const int kch = (lane >> 4) * 8;
    const int rrow = (lane >> 4) * 4;
    f32x4 sc[2][8];
    {
        bf16x8 af0 = *(bf16x8*)&Qb[(q0 + arow) * SQ + kch];
        bf16x8 af1 = *(bf16x8*)&Qb[(q0 + 16 + arow) * SQ + kch];
        f32x4 z = {0.0f, 0.0f, 0.0f, 0.0f};
        #pragma unroll
        for (int j = 0; j < 8; ++j) {
            bf16x8 bf_ = *(bf16x8*)&Kb[(j * 16 + arow) * SQ + kch];
            sc[0][j] = __builtin_amdgcn_mfma_f32_16x16x32_bf16(af0, bf_, z, 0, 0, 0);
            sc[1][j] = __builtin_amdgcn_mfma_f32_16x16x32_bf16(af1, bf_, z, 0, 0, 0);
        }
    }
    #pragma unroll
    for (int i = 0; i < 2; ++i) {
        #pragma unroll
        for (int r = 0; r < 4; ++r) {
            float m = -1e30f;
            #pragma unroll
            for (int j = 0; j < 8; ++j) m = fmaxf(m, sc[i][j][r]);
            #pragma unroll
            for (int d = 8; d >= 1; d >>= 1) m = fmaxf(m, __shfl_xor(m, d));
            float sum = 0.0f;
            #pragma unroll
            for (int j = 0; j < 8; ++j) {
                float e = expf((sc[i][j][r] - m) * scale);
                sc[i][j][r] = e;
                sum += e;
            }
            #pragma unroll
            for (int d = 8; d >= 1; d >>= 1) sum += __shfl_xor(sum, d);
            float inv = 1.0f / sum;
            int row = q0 + i * 16 + rrow + r;
            #pragma unroll
            for (int j = 0; j < 8; ++j)
                Pb[row * SV + j * 16 + (lane & 15)] = (__bf16)(sc[i][j][r] * inv);
        }
    }
    #pragma unroll
    for (int i = 0; i < 2; ++i) {
        #pragma unroll
        for (int j2 = 0; j2 < 2; ++j2) {
            f32x4 a2 = {0.0f, 0.0f, 0.0f, 0.0f};
            #pragma unroll
            for (int ks = 0; ks < 4; ++ks) {
                bf16x8 pa = *(bf16x8*)&Pb[(q0 + i * 16 + arow) * SV + ks * 32 + kch];
                bf16x8 vb = *(bf16x8*)&Vt[(j2 * 16 + arow) * SV + ks * 32 + kch];
                a2 = __builtin_amdgcn_mfma_f32_16x16x32_bf16(pa, vb, a2, 0, 0, 0);
            }
            #pragma unroll
            for (int r = 0; r < 4; ++r) {
                int q = q0 + i * 16 + rrow + r;
                o[((size_t)(b * S + q)) * D + h * DH + j2 * 16 + (lane & 15)] = (__bf16)a2[r];
            }
        }
    }
}

// =====================================================================
// encoder attention via MFMA (unchanged)
// =====================================================================
template <int S, int DH, int NH>
__global__ __launch_bounds__(64) void eattn_kernel(const __bf16* __restrict__ qkv,
                                                   __bf16* __restrict__ o, float scale)
{
    constexpr int D = NH * DH;
    constexpr int SQ = DH + 8;
    constexpr int SV = S + 8;
    __shared__ __bf16 Qb[S * SQ];
    __shared__ __bf16 Kb[S * SQ];
    __shared__ __bf16 Vt[DH * SV];
    __shared__ __bf16 Pb[S * SV];
    const int h = blockIdx.x % NH;
    const int b = blockIdx.x / NH;
    const int lane = threadIdx.x;
    const __bf16* base = qkv + (size_t)b * S * 3 * D + h * DH;
    for (int i = lane; i < S * (DH / 8); i += 64) {
        int s = i / (DH / 8), c8 = (i % (DH / 8)) * 8;
        const __bf16* rp = base + (size_t)s * 3 * D;
        bf16x8 q = *(const bf16x8*)(rp + c8);
        bf16x8 k = *(const bf16x8*)(rp + D + c8);
        bf16x8 v = *(const bf16x8*)(rp + 2 * D + c8);
        *(bf16x8*)&Qb[s * SQ + c8] = q;
        *(bf16x8*)&Kb[s * SQ + c8] = k;
        #pragma unroll
        for (int j = 0; j < 8; ++j) Vt[(c8 + j) * SV + s] = v[j];
    }
    __syncthreads();
    const int arow = lane & 15;
    const int kch = (lane >> 4) * 8;
    const int rrow = (lane >> 4) * 4;
    f32x4 sc[2][2] = {};
    #pragma unroll
    for (int ks = 0; ks < 2; ++ks) {
        bf16x8 af0 = *(bf16x8*)&Qb[(arow) * SQ + ks * 32 + kch];
        bf16x8 af1 = *(bf16x8*)&Qb[(16 + arow) * SQ + ks * 32 + kch];
        #pragma unroll
        for (int j = 0; j < 2; ++j) {
            bf16x8 bf_ = *(bf16x8*)&Kb[(j * 16 + arow) * SQ + ks * 32 + kch];
            sc[0][j] = __builtin_amdgcn_mfma_f32_16x16x32_bf16(af0, bf_, sc[0][j], 0, 0, 0);
            sc[1][j] = __builtin_amdgcn_mfma_f32_16x16x32_bf16(af1, bf_, sc[1][j], 0, 0, 0);
        }
    }
    #pragma unroll
    for (int i = 0; i < 2; ++i) {
        #pragma unroll
        for (int r = 0; r < 4; ++r) {
            float m = fmaxf(sc[i][0][r], sc[i][1][r]);
            #pragma unroll
            for (int d = 8; d >= 1; d >>= 1) m = fmaxf(m, __shfl_xor(m, d));
            float sum = 0.0f;
            #pragma unroll
            for (int j = 0; j < 2; ++j) {
                float e = expf((sc[i][j][r] - m) * scale);
                sc[i][j][r] = e;
                sum += e;
            }
            #pragma unroll
            for (int d = 8; d >= 1; d >>= 1) sum += __shfl_xor(sum, d);
            float inv = 1.0f / sum;
            int row = i * 16 + rrow + r;
            #pragma unroll
            for (int j = 0; j < 2; ++j)
                Pb[row * SV + j * 16 + (lane & 15)] = (__bf16)(sc[i][j][r] * inv);
        }
    }
    __syncthreads();
    #pragma unroll
    for (int i = 0; i < 2; ++i) {
        bf16x8 pa = *(bf16x8*)&Pb[(i * 16 + arow) * SV + kch];
        #pragma unroll
        for (int j2 = 0; j2 < 4; ++j2) {
            bf16x8 vb = *(bf16x8*)&Vt[(j2 * 16 + arow) * SV + kch];
            f32x4 z = {0.0f, 0.0f, 0.0f, 0.0f};
            f32x4 a2 = __builtin_amdgcn_mfma_f32_16x16x32_bf16(pa, vb, z, 0, 0, 0);
            #pragma unroll
            for (int r = 0; r < 4; ++r) {
                int q = i * 16 + rrow + r;
                o[((size_t)(b * S + q)) * D + h * DH + j2 * 16 + (lane & 15)] = (__bf16)a2[r];
            }
        }
    }
}

// =====================================================================
// LayerNorm with residual (+ SK split-K partial sum)
// =====================================================================
template <int D, int SK>
__global__ __launch_bounds__(256) void ln_res(float* __restrict__ x, const float* __restrict__ part,
                                              size_t pstride,
                                              const float* __restrict__ g, const float* __restrict__ b,
                                              __bf16* __restrict__ xb)
{
    constexpr int J = D / 256;
    __shared__ float pr[2][4];
    const size_t off = (size_t)blockIdx.x * D;
    const int tid = threadIdx.x;
    float vals[J];
    float s = 0.0f, s2 = 0.0f;
    #pragma unroll
    for (int j = 0; j < J; ++j) {
        int i = tid + j * 256;
        float v = x[off + i];
        #pragma unroll
        for (int sk = 0; sk < SK; ++sk) v += part[(size_t)sk * pstride + off + i];
        vals[j] = v; s += v; s2 += v * v;
    }
    #pragma unroll
    for (int d = 32; d >= 1; d >>= 1) { s += __shfl_down(s, d); s2 += __shfl_down(s2, d); }
    if ((tid & 63) == 0) { pr[0][tid >> 6] = s; pr[1][tid >> 6] = s2; }
    __syncthreads();
    float st = pr[0][0] + pr[0][1] + pr[0][2] + pr[0][3];
    float s2t = pr[1][0] + pr[1][1] + pr[1][2] + pr[1][3];
    float m = st / D;
    float var = s2t / D - m * m;
    if (var < 0.0f) var = 0.0f;
    float rs = rsqrtf(var + 1e-5f);
    #pragma unroll
    for (int j = 0; j < J; ++j) {
        int i = tid + j * 256;
        float v = (vals[j] - m) * rs * g[i] + b[i];
        x[off + i] = v;
        xb[off + i] = (__bf16)v;
    }
}

// =====================================================================
// loss: sum 4 pred split-K partials, write final pred, masked row mse
// =====================================================================
__global__ __launch_bounds__(128) void loss_l(const float* __restrict__ predp,
                                              const float* __restrict__ target,
                                              const float* __restrict__ maskv,
                                              float* __restrict__ pred_out,
                                              float* __restrict__ lm)
{
    const size_t PS = (size_t)4096 * 96;
    const int g = blockIdx.x;
    __shared__ float red[128];
    int t = threadIdx.x;
    float s = 0.0f;
    if (t < 96) {
        size_t o = (size_t)g * 96 + t;
        float v = predp[o] + predp[PS + o] + predp[2 * PS + o] + predp[3 * PS + o];
        pred_out[o] = v;
        float d = v - target[o];
        s = d * d;
    }
    red[t] = s; __syncthreads();
    for (int st = 64; st > 0; st >>= 1) { if (t < st) red[t] += red[t + st]; __syncthreads(); }
    if (t == 0) lm[g] = (red[0] / 96.0f) * maskv[g];
}

__global__ __launch_bounds__(1024) void loss_final(const float* __restrict__ lm,
                                                   const float* __restrict__ maskv,
                                                   float* __restrict__ out)
{
    __shared__ float r1[1024], r2[1024];
    int t = threadIdx.x;
    float a = 0.0f, b = 0.0f;
    for (int i = t; i < BB * NG; i += 1024) { a += lm[i]; b += maskv[i]; }
    r1[t] = a; r2[t] = b; __syncthreads();
    for (int st = 512; st > 0; st >>= 1) { if (t < st) { r1[t] += r1[t + st]; r2[t] += r2[t + st]; } __syncthreads(); }
    if (t == 0) out[0] = r1[0] / r2[0];
}

// =====================================================================
// host
// =====================================================================
extern "C" void kernel_launch(void* const* d_in, const int* in_sizes, int n_in,
                              void* d_out, int out_size, void* d_ws, size_t ws_size,
                              hipStream_t stream)
{
    (void)in_sizes; (void)n_in; (void)out_size; (void)ws_size;
    const float* xyz        = (const float*)d_in[0];
    const int*   fps_init   = (const int*)d_in[1];
    const int*   ids_shuf   = (const int*)d_in[2];
    const float* cw1 = (const float*)d_in[3];  const float* cb1 = (const float*)d_in[4];
    const float* g1  = (const float*)d_in[5];  const float* be1 = (const float*)d_in[6];
    const float* cw2 = (const float*)d_in[7];  const float* cb2 = (const float*)d_in[8];
    const float* g2  = (const float*)d_in[9];  const float* be2 = (const float*)d_in[10];
    const float* cw3 = (const float*)d_in[11]; const float* cb3 = (const float*)d_in[12];
    const float* g3  = (const float*)d_in[13]; const float* be3 = (const float*)d_in[14];
    const float* posw = (const float*)d_in[15]; const float* posb = (const float*)d_in[16];
    const float* eqw = (const float*)d_in[17]; const float* eqb = (const float*)d_in[18];
    const float* eow = (const float*)d_in[19]; const float* eob = (const float*)d_in[20];
    const float* el1g = (const float*)d_in[21]; const float* el1b = (const float*)d_in[22];
    const float* ef1w = (const float*)d_in[23]; const float* ef1b = (const float*)d_in[24];
    const float* ef2w = (const float*)d_in[25]; const float* ef2b = (const float*)d_in[26];
    const float* el2g = (const float*)d_in[27]; const float* el2b = (const float*)d_in[28];
    const float* dew = (const float*)d_in[29]; const float* deb = (const float*)d_in[30];
    const float* mtok = (const float*)d_in[31];
    const float* dpw = (const float*)d_in[32]; const float* dpb = (const float*)d_in[33];
    const float* dqw = (const float*)d_in[34]; const float* dqb = (const float*)d_in[35];
    const float* dow = (const float*)d_in[36]; const float* dob = (const float*)d_in[37];
    const float* dl1g = (const float*)d_in[38]; const float* dl1b = (const float*)d_in[39];
    const float* df1w = (const float*)d_in[40]; const float* df1b = (const float*)d_in[41];
    const float* df2w = (const float*)d_in[42]; const float* df2b = (const float*)d_in[43];
    const float* dl2g = (const float*)d_in[44]; const float* dl2b = (const float*)d_in[45];
    const float* prw = (const float*)d_in[46]; const float* prb = (const float*)d_in[47];
    float* out = (float*)d_out;
    float* pred = out + 1;
    float* maskv = out + 1 + (size_t)BB * NG * KNB * 3;

    // ---- workspace carve ----
    char* ws = (char*)d_ws;
    size_t off = 0;
    auto alloc = [&](size_t bytes) -> void* {
        void* p = ws + off;
        off = (off + bytes + 255) & ~(size_t)255;
        return p;
    };
    double* st1 = (double*)alloc(128 * 8);
    double* st2 = (double*)alloc((size_t)32 * 256 * 8);   // 32-way spread for fused stats
    double* st3 = (double*)alloc((size_t)32 * 1536 * 8);
    float* sc1 = (float*)alloc(64 * 4);  float* sh1 = (float*)alloc(64 * 4);
    float* sc2 = (float*)alloc(128 * 4); float* sh2 = (float*)alloc(128 * 4);
    float* a3 = (float*)alloc(768 * 4);  float* c3 = (float*)alloc(768 * 4);
    int* restore = (int*)alloc(4096 * 4);
    float* cxyz = (float*)alloc(12288 * 4);
    float* gn   = (float*)alloc((size_t)393216 * 4);
    __bf16* cw2b = (__bf16*)alloc((size_t)128 * 64 * 2);
    __bf16* cw3b = (__bf16*)alloc((size_t)768 * 128 * 2);
    float* xfull = (float*)alloc((size_t)4096 * 768 * 4);   // encoder SK partials
    float* xe    = (float*)alloc((size_t)1024 * 768 * 4);
    __bf16* xeb  = (__bf16*)alloc((size_t)1024 * 768 * 2);
    float* qkve  = (float*)alloc((size_t)1024 * 2304 * 4);  // dew SK partials (f32)
    __bf16* qkveb = (__bf16*)alloc((size_t)1024 * 2304 * 2);
    __bf16* oeb  = (__bf16*)alloc((size_t)1024 * 768 * 2);
    __bf16* fe1b = (__bf16*)alloc((size_t)1024 * 3072 * 2);
    float* xd    = (float*)alloc((size_t)4096 * 512 * 4);
    __bf16* xdb  = (__bf16*)alloc((size_t)4096 * 512 * 2);
    float* qkvd  = (float*)alloc((size_t)4096 * 1536 * 4);  // dec SK partials; gmax/gmin alias
    __bf16* qkvdb = (__bf16*)alloc((size_t)4096 * 1536 * 2);
    __bf16* odb  = (__bf16*)alloc((size_t)4096 * 512 * 2);
    __bf16* fd1b = (__bf16*)alloc((size_t)4096 * 2048 * 2); // pred SK partials alias
    float* lm    = (float*)alloc(4096 * 4);

    __bf16* eqwb  = (__bf16*)alloc((size_t)NLE * 3 * DE * DE * 2);
    __bf16* eowb  = (__bf16*)alloc((size_t)NLE * DE * DE * 2);
    __bf16* ef1wb = (__bf16*)alloc((size_t)NLE * 4 * DE * DE * 2);
    __bf16* ef2wb = (__bf16*)alloc((size_t)NLE * 4 * DE * DE * 2);
    __bf16* dewb  = (__bf16*)alloc((size_t)DD * DE * 2);
    __bf16* dqwb  = (__bf16*)alloc((size_t)NLD * 3 * DD * DD * 2);
    __bf16* dowb  = (__bf16*)alloc((size_t)NLD * DD * DD * 2);
    __bf16* df1wb = (__bf16*)alloc((size_t)NLD * 4 * DD * DD * 2);
    __bf16* df2wb = (__bf16*)alloc((size_t)NLD * 4 * DD * DD * 2);
    __bf16* prwb  = (__bf16*)alloc((size_t)128 * 512 * 2);

    // stage-2 temps alias the ENCODER weight region
    char* U = (char*)eqwb;
    float*  h1   = (float*)U;
    __bf16* h1b  = (__bf16*)(U + (size_t)33554432);
    float*  h2   = (float*)(U + (size_t)50331648);
    __bf16* h2b  = (__bf16*)(U + (size_t)117440512);
    float* gmax = qkvd;
    float* gmin = qkvd + (size_t)3145728;
    float* predp = (float*)fd1b;

    size_t stats_bytes = (size_t)((char*)st3 + (size_t)32 * 1536 * 8 - (char*)st1);
    hipMemsetAsync((void*)st1, 0, stats_bytes, stream);

    auto cvt = [&](const float* src, __bf16* dst, size_t n) {
        int n8 = (int)(n / 8);
        cvt_bf16_kernel<<<(n8 + 255) / 256, 256, 0, stream>>>(src, dst, n8);
    };
    auto gemm = [&](const __bf16* A, const __bf16* Wt, const float* bias,
                    float* Cf, __bf16* Cb, int M, int N, int K, int relu) {
        int nb128 = ((N + 127) / 128) * (M / 128);
        if (nb128 < 400) {   // covers decoder qkv (384) and all encoder shapes
            dim3 grid((N + 127) / 128, M / 64, 1);
            gemm_bf16<64, 1, 4, 3, false><<<grid, 256, 0, stream>>>(A, Wt, bias, Cf, Cb, M, N, K, K, relu, nullptr);
        } else {
            dim3 grid((N + 127) / 128, M / 128, 1);
            gemm_bf16<128, 2, 2, 2, false><<<grid, 256, 0, stream>>>(A, Wt, bias, Cf, Cb, M, N, K, K, relu, nullptr);
        }
    };
    auto gemmSK = [&](const __bf16* A, const __bf16* Wt, const float* bias,
                      float* Cf, int M, int N, int K, int SK) {
        dim3 grid((N + 127) / 128, M / 64, SK);
        gemm_bf16<64, 1, 4, 3, false><<<grid, 256, 0, stream>>>(A, Wt, bias, Cf, nullptr, M, N, K, K / SK, 0, nullptr);
    };

    cvt(cw2, cw2b, 128 * 64);
    cvt(cw3, cw3b, 768 * 128);

    // ---- stage 1: FPS + KNN ----
    fps_kernel<<<BB, 512, 0, stream>>>(xyz, fps_init, cxyz);
    knn_kernel<<<BB * NG, 256, 0, stream>>>(xyz, cxyz, gn);

    // ---- stage 2: mini-PointNet ----
    embed1_kernel<<<(131072 * 64 + 255) / 256, 256, 0, stream>>>(gn, cw1, cb1, h1);
    colstats_kernel<64><<<256, 256, 0, stream>>>(h1, st1, 131072);
    bn_finalize<<<1, 64, 0, stream>>>(st1, g1, be1, sc1, sh1, 64);
    bn_apply_bf16<<<(131072 * 64 + 255) / 256, 256, 0, stream>>>(h1, sc1, sh1, h1b, 131072 * 64, 64);
    // h2 GEMM with fused column stats (grid.x == 1 since N=128)
    gemm_bf16<128, 2, 2, 2, true><<<dim3(1, 1024, 1), 256, 0, stream>>>(
        h1b, cw2b, cb2, h2, nullptr, 131072, 128, 64, 64, 0, st2);
    bn_spread_finalize<<<2, 64, 0, stream>>>(st2, g2, be2, sc2, sh2, 128);
    bn_apply_bf16<<<(131072 * 128 + 255) / 256, 256, 0, stream>>>(h2, sc2, sh2, h2b, 131072 * 128, 128);
    embed3_mfma<<<dim3(6, 1024), 256, 0, stream>>>(h2b, cw3b, cb3, gmax, gmin, st3);
    bn3_finalize<<<3, 256, 0, stream>>>(st3, g3, be3, a3, c3);

    // ---- stage 3: shuffle / mask / tokens (gather fused) ----
    restore_kernel<<<16, 256, 0, stream>>>(ids_shuf, restore, maskv);
    tokens_pos<<<(4096 * 768 + 255) / 256, 256, 0, stream>>>(gmax, gmin, a3, c3, cxyz, posw, posb,
                                                             restore, xe, xeb);

    // ---- weight conversion: single dispatch ----
    {
        CvtTab t;
        const float* srcs[10] = {eqw, eow, ef1w, ef2w, dew, dqw, dow, df1w, df2w, prw};
        __bf16* dsts[10] = {eqwb, eowb, ef1wb, ef2wb, dewb, dqwb, dowb, df1wb, df2wb, prwb};
        size_t ns[10] = {
            (size_t)NLE * 3 * DE * DE, (size_t)NLE * DE * DE,
            (size_t)NLE * 4 * DE * DE, (size_t)NLE * 4 * DE * DE,
            (size_t)DD * DE,
            (size_t)NLD * 3 * DD * DD, (size_t)NLD * DD * DD,
            (size_t)NLD * 4 * DD * DD, (size_t)NLD * 4 * DD * DD,
            (size_t)96 * 512
        };
        int cum = 0;
        t.cum[0] = 0;
        for (int k = 0; k < 10; ++k) {
            t.src[k] = srcs[k]; t.dst[k] = dsts[k];
            cum += (int)(ns[k] / 8);
            t.cum[k + 1] = cum;
        }
        cvt_multi_kernel<<<(cum + 255) / 256, 256, 0, stream>>>(t);
        hipMemsetAsync((void*)(prwb + (size_t)96 * 512), 0, (size_t)32 * 512 * 2, stream);
    }

    const size_t PSE = (size_t)1024 * DE;
    const size_t PSD = (size_t)4096 * DD;

    // ---- stage 4: encoder (12 layers) ----
    for (int l = 0; l < NLE; ++l) {
        gemm(xeb, eqwb + (size_t)l * 3 * DE * DE, eqb + (size_t)l * 3 * DE, nullptr, qkveb, 1024, 3 * DE, DE, 0);
        eattn_kernel<LK, 64, 12><<<BB * 12, 64, 0, stream>>>(qkveb, oeb, 0.125f);
        gemmSK(oeb, eowb + (size_t)l * DE * DE, eob + (size_t)l * DE, xfull, 1024, DE, DE, 4);
        ln_res<DE, 4><<<BB * LK, 256, 0, stream>>>(xe, xfull, PSE, el1g + (size_t)l * DE, el1b + (size_t)l * DE, xeb);
        gemm(xeb, ef1wb + (size_t)l * 4 * DE * DE, ef1b + (size_t)l * 4 * DE, nullptr, fe1b, 1024, 4 * DE, DE, 1);
        gemmSK(fe1b, ef2wb + (size_t)l * DE * 4 * DE, ef2b + (size_t)l * DE, xfull, 1024, DE, 4 * DE, 4);
        ln_res<DE, 4><<<BB * LK, 256, 0, stream>>>(xe, xfull, PSE, el2g + (size_t)l * DE, el2b + (size_t)l * DE, xeb);
    }

    // ---- stage 5: decoder embed + mask tokens ----
    gemmSK(xeb, dewb, deb, qkve, 1024, DD, DE, 4);
    yd_build<<<(BB * NG * DD + 255) / 256, 256, 0, stream>>>(qkve, restore, mtok, cxyz, dpw, dpb, xd, xdb);

    // ---- stage 6: decoder (8 layers) ----
    const float dsc = (float)(1.0 / sqrt(32.0));
    for (int l = 0; l < NLD; ++l) {
        gemm(xdb, dqwb + (size_t)l * 3 * DD * DD, dqb + (size_t)l * 3 * DD, nullptr, qkvdb, 4096, 3 * DD, DD, 0);
        dattn_kernel<NG, 32, 16><<<BB * 16, 256, 0, stream>>>(qkvdb, odb, dsc);
        gemmSK(odb, dowb + (size_t)l * DD * DD, dob + (size_t)l * DD, qkvd, 4096, DD, DD, 2);
        ln_res<DD, 2><<<BB * NG, 256, 0, stream>>>(xd, qkvd, PSD, dl1g + (size_t)l * DD, dl1b + (size_t)l * DD, xdb);
        gemm(xdb, df1wb + (size_t)l * 4 * DD * DD, df1b + (size_t)l * 4 * DD, nullptr, fd1b, 4096, 4 * DD, DD, 1);
        gemmSK(fd1b, df2wb + (size_t)l * DD * 4 * DD, df2b + (size_t)l * DD, qkvd, 4096, DD, 4 * DD, 2);
        ln_res<DD, 2><<<BB * NG, 256, 0, stream>>>(xd, qkvd, PSD, dl2g + (size_t)l * DD, dl2b + (size_t)l * DD, xdb);
    }

    // ---- stage 7: prediction (split-K) + loss ----
    gemmSK(xdb, prwb, prb, predp, 4096, 96, 512, 4);
    loss_l<<<BB * NG, 128, 0, stream>>>(predp, gn, maskv, pred, lm);
    loss_final<<<1, 1024, 0, stream>>>(lm, maskv, out);
}